// Round 1
// baseline (2451.850 us; speedup 1.0000x reference)
//
#include <hip/hip_runtime.h>

// InverseTransitionModel: fc-encoder + 2-layer GRU rollout (10 steps), B=32768.
// Strategy: bf16 MFMA (16x16x32) everywhere, fp32 accum/elementwise.
// All MFMA fragments loaded directly from global (16B short8 loads); weights
// pre-cast to bf16 in d_ws once per call. h0/h1 ping-pong between steps.

#define BATCH 32768

typedef __attribute__((ext_vector_type(8))) short short8;
typedef __attribute__((ext_vector_type(4))) float fvec4;

__device__ __forceinline__ float bf2f(unsigned short u) {
    union { unsigned int u; float f; } x; x.u = ((unsigned int)u) << 16; return x.f;
}
__device__ __forceinline__ unsigned short f2bf(float f) {
    union { float f; unsigned int u; } x; x.f = f;
    unsigned int r = x.u + 0x7fffu + ((x.u >> 16) & 1u);   // RNE
    return (unsigned short)(r >> 16);
}
__device__ __forceinline__ float sigm(float x)   { return __builtin_amdgcn_rcpf(1.f + __expf(-x)); }
__device__ __forceinline__ float tanh_f(float x) { return 2.f * __builtin_amdgcn_rcpf(1.f + __expf(-2.f * x)) - 1.f; }

__device__ __forceinline__ short8 ld8(const unsigned short* p) {
    return *reinterpret_cast<const short8*>(p);
}
__device__ __forceinline__ fvec4 mfma16(short8 a, short8 b, fvec4 c) {
    return __builtin_amdgcn_mfma_f32_16x16x32_bf16(a, b, c, 0, 0, 0);
}

// ---------------- weight cast fp32 -> bf16 ----------------
// ws short layout: W1[262144] W2[65536] Winit[131072] Wih0[6144]
//                  Whh0[196608] Wih1[196608] Whh1[196608] Wa[2048]
__global__ __launch_bounds__(256) void k_prep(
    const float* __restrict__ W1, const float* __restrict__ W2,
    const float* __restrict__ Winit, const float* __restrict__ Wih0,
    const float* __restrict__ Whh0, const float* __restrict__ Wih1,
    const float* __restrict__ Whh1, const float* __restrict__ Wa,
    unsigned short* __restrict__ wb)
{
    int i = blockIdx.x * 256 + threadIdx.x;
    if (i >= 1056768) return;
    float v;
    if      (i <  262144) v = W1[i];
    else if (i <  327680) v = W2[i - 262144];
    else if (i <  458752) v = Winit[i - 327680];
    else if (i <  464896) v = Wih0[i - 458752];
    else if (i <  661504) v = Whh0[i - 464896];
    else if (i <  858112) v = Wih1[i - 661504];
    else if (i < 1054720) v = Whh1[i - 858112];
    else                  v = Wa[i - 1054720];
    wb[i] = f2bf(v);
}

// ---------------- fc1: [B,1024] @ W1^T + b1 -> LN -> ReLU -> h (bf16) ----------
// block: 64 rows x 256 cols, 8 waves = 2 rowg(32) x 4 colg(64); wave 32x64.
__global__ __launch_bounds__(512) void k_fc1(
    const float* __restrict__ ini, const float* __restrict__ fin,
    const unsigned short* __restrict__ W1b,
    const float* __restrict__ b1, const float* __restrict__ lng,
    const float* __restrict__ lnb, unsigned short* __restrict__ hbuf)
{
    const int tid = threadIdx.x, lane = tid & 63, w = tid >> 6;
    const int rowg = w >> 2, colg = w & 3;
    const int lrow0 = rowg * 32;
    const int row0 = blockIdx.x * 64 + lrow0;
    const int cbase = colg * 64;
    const int l15 = lane & 15, q = lane >> 4;
    const fvec4 fz = {0.f, 0.f, 0.f, 0.f};
    fvec4 acc[2][4];
#pragma unroll
    for (int a = 0; a < 2; ++a)
#pragma unroll
        for (int b = 0; b < 4; ++b) acc[a][b] = fz;

    for (int kc = 0; kc < 32; ++kc) {
        const int k0 = kc * 32 + q * 8;
        short8 af[2];
#pragma unroll
        for (int mt = 0; mt < 2; ++mt) {
            const int gr = row0 + mt * 16 + l15;
            const float* src = (k0 < 512) ? (ini + gr * 512 + k0) : (fin + gr * 512 + (k0 - 512));
            fvec4 v0 = *reinterpret_cast<const fvec4*>(src);
            fvec4 v1 = *reinterpret_cast<const fvec4*>(src + 4);
            short8 t;
            t[0]=(short)f2bf(v0[0]); t[1]=(short)f2bf(v0[1]); t[2]=(short)f2bf(v0[2]); t[3]=(short)f2bf(v0[3]);
            t[4]=(short)f2bf(v1[0]); t[5]=(short)f2bf(v1[1]); t[6]=(short)f2bf(v1[2]); t[7]=(short)f2bf(v1[3]);
            af[mt] = t;
        }
#pragma unroll
        for (int nt = 0; nt < 4; ++nt) {
            const int c = cbase + nt * 16 + l15;
            short8 bf = ld8(W1b + c * 1024 + k0);
            acc[0][nt] = mfma16(af[0], bf, acc[0][nt]);
            acc[1][nt] = mfma16(af[1], bf, acc[1][nt]);
        }
    }
    // ---- LayerNorm epilogue (stats across the 256 cols of each row) ----
    __shared__ float ps[64][4][2];
    __shared__ float stats[64][2];
    float b1v[4];
#pragma unroll
    for (int nt = 0; nt < 4; ++nt) b1v[nt] = b1[cbase + nt * 16 + l15];
#pragma unroll
    for (int mt = 0; mt < 2; ++mt)
#pragma unroll
        for (int r = 0; r < 4; ++r) {
            float s = 0.f, s2 = 0.f;
#pragma unroll
            for (int nt = 0; nt < 4; ++nt) {
                float v = acc[mt][nt][r] + b1v[nt];
                acc[mt][nt][r] = v;
                s += v; s2 += v * v;
            }
#pragma unroll
            for (int off = 1; off < 16; off <<= 1) {
                s  += __shfl_xor(s,  off, 64);
                s2 += __shfl_xor(s2, off, 64);
            }
            if (l15 == 0) {
                int rl = lrow0 + mt * 16 + q * 4 + r;
                ps[rl][colg][0] = s;
                ps[rl][colg][1] = s2;
            }
        }
    __syncthreads();
    if (tid < 64) {
        float s  = ps[tid][0][0] + ps[tid][1][0] + ps[tid][2][0] + ps[tid][3][0];
        float s2 = ps[tid][0][1] + ps[tid][1][1] + ps[tid][2][1] + ps[tid][3][1];
        float mu = s * (1.f / 256.f);
        float var = s2 * (1.f / 256.f) - mu * mu;
        stats[tid][0] = mu;
        stats[tid][1] = rsqrtf(var + 1e-5f);
    }
    __syncthreads();
    float gv[4], bv[4];
#pragma unroll
    for (int nt = 0; nt < 4; ++nt) {
        int c = cbase + nt * 16 + l15;
        gv[nt] = lng[c]; bv[nt] = lnb[c];
    }
#pragma unroll
    for (int mt = 0; mt < 2; ++mt)
#pragma unroll
        for (int r = 0; r < 4; ++r) {
            int rl = lrow0 + mt * 16 + q * 4 + r;
            float mu = stats[rl][0], rs = stats[rl][1];
            int grow = blockIdx.x * 64 + rl;
#pragma unroll
            for (int nt = 0; nt < 4; ++nt) {
                float v = (acc[mt][nt][r] - mu) * rs * gv[nt] + bv[nt];
                v = fmaxf(v, 0.f);
                hbuf[grow * 256 + cbase + nt * 16 + l15] = f2bf(v);
            }
        }
}

// ---------------- fc2: relu(h @ W2^T + b2), in-place on hbuf -------------------
__global__ __launch_bounds__(512) void k_fc2(
    const unsigned short* __restrict__ hin,
    const unsigned short* __restrict__ W2b,
    const float* __restrict__ b2, unsigned short* __restrict__ hout)
{
    const int tid = threadIdx.x, lane = tid & 63, w = tid >> 6;
    const int rowg = w >> 2, colg = w & 3;
    const int row0 = blockIdx.x * 64 + rowg * 32;
    const int cbase = colg * 64;
    const int l15 = lane & 15, q = lane >> 4;
    const fvec4 fz = {0.f, 0.f, 0.f, 0.f};
    fvec4 acc[2][4];
#pragma unroll
    for (int a = 0; a < 2; ++a)
#pragma unroll
        for (int b = 0; b < 4; ++b) acc[a][b] = fz;

    for (int kc = 0; kc < 8; ++kc) {
        const int k0 = kc * 32 + q * 8;
        short8 af[2];
#pragma unroll
        for (int mt = 0; mt < 2; ++mt)
            af[mt] = ld8(hin + (row0 + mt * 16 + l15) * 256 + k0);
#pragma unroll
        for (int nt = 0; nt < 4; ++nt) {
            const int c = cbase + nt * 16 + l15;
            short8 bf = ld8(W2b + c * 256 + k0);
            acc[0][nt] = mfma16(af[0], bf, acc[0][nt]);
            acc[1][nt] = mfma16(af[1], bf, acc[1][nt]);
        }
    }
    __syncthreads();   // all reads of hin complete before in-place writes
#pragma unroll
    for (int nt = 0; nt < 4; ++nt) {
        const int c = cbase + nt * 16 + l15;
        const float bb = b2[c];
#pragma unroll
        for (int mt = 0; mt < 2; ++mt)
#pragma unroll
            for (int r = 0; r < 4; ++r) {
                const int grow = row0 + mt * 16 + q * 4 + r;
                float v = fmaxf(acc[mt][nt][r] + bb, 0.f);
                hout[grow * 256 + c] = f2bf(v);
            }
    }
}

// ---------------- init hidden: X = h @ Winit^T + binit, torch-view split -------
// X[i][j]: i<B/2 -> h0[2i + (j>=256)][j&255]; else h1[2(i-B/2) + (j>=256)][j&255]
__global__ __launch_bounds__(512) void k_init(
    const unsigned short* __restrict__ hin,
    const unsigned short* __restrict__ Wb,
    const float* __restrict__ binit,
    unsigned short* __restrict__ h0, unsigned short* __restrict__ h1)
{
    const int tid = threadIdx.x, lane = tid & 63, w = tid >> 6;
    const int rowg = w >> 1, colg = w & 1;
    const int row0 = blockIdx.x * 128 + rowg * 32;
    const int cbase = blockIdx.y * 128 + colg * 64;
    const int l15 = lane & 15, q = lane >> 4;
    const fvec4 fz = {0.f, 0.f, 0.f, 0.f};
    fvec4 acc[2][4];
#pragma unroll
    for (int a = 0; a < 2; ++a)
#pragma unroll
        for (int b = 0; b < 4; ++b) acc[a][b] = fz;

    for (int kc = 0; kc < 8; ++kc) {
        const int k0 = kc * 32 + q * 8;
        short8 af[2];
#pragma unroll
        for (int mt = 0; mt < 2; ++mt)
            af[mt] = ld8(hin + (row0 + mt * 16 + l15) * 256 + k0);
#pragma unroll
        for (int nt = 0; nt < 4; ++nt) {
            short8 bf = ld8(Wb + (cbase + nt * 16 + l15) * 256 + k0);
            acc[0][nt] = mfma16(af[0], bf, acc[0][nt]);
            acc[1][nt] = mfma16(af[1], bf, acc[1][nt]);
        }
    }
#pragma unroll
    for (int nt = 0; nt < 4; ++nt) {
        const int j = cbase + nt * 16 + l15;
        const float bz = binit[j];
        const int half = j >> 8, cc = j & 255;
#pragma unroll
        for (int mt = 0; mt < 2; ++mt)
#pragma unroll
            for (int r = 0; r < 4; ++r) {
                const int i = row0 + mt * 16 + q * 4 + r;
                const unsigned short v = f2bf(acc[mt][nt][r] + bz);
                if (i < 16384) h0[(2 * i + half) * 256 + cc] = v;
                else           h1[(2 * (i - 16384) + half) * 256 + cc] = v;
            }
    }
}

// ---------------- GRU cell 0: x = a[B,8], h = h0 -------------------------------
// block 128 rows x 64 cols; wave 32x32; accums: r, z, i_n, h_n.
__global__ __launch_bounds__(512) void k_gru0(
    const unsigned short* __restrict__ h0in, unsigned short* __restrict__ h0out,
    const unsigned short* __restrict__ abuf, const int step,
    const unsigned short* __restrict__ Whh0b, const unsigned short* __restrict__ Wih0b,
    const float* __restrict__ bih0, const float* __restrict__ bhh0)
{
    const int tid = threadIdx.x, lane = tid & 63, w = tid >> 6;
    const int rowg = w >> 1, colg = w & 1;
    const int row0 = blockIdx.x * 128 + rowg * 32;
    const int cbase = blockIdx.y * 64 + colg * 32;
    const int l15 = lane & 15, q = lane >> 4;
    const fvec4 fz = {0.f, 0.f, 0.f, 0.f};
    fvec4 accr[2][2], accz[2][2], acci[2][2], acch[2][2];
#pragma unroll
    for (int a = 0; a < 2; ++a)
#pragma unroll
        for (int b = 0; b < 2; ++b) { accr[a][b]=fz; accz[a][b]=fz; acci[a][b]=fz; acch[a][b]=fz; }

    for (int kc = 0; kc < 8; ++kc) {
        const int k0 = kc * 32 + q * 8;
        short8 af[2];
#pragma unroll
        for (int mt = 0; mt < 2; ++mt)
            af[mt] = ld8(h0in + (row0 + mt * 16 + l15) * 256 + k0);
#pragma unroll
        for (int nt = 0; nt < 2; ++nt) {
            const int c = cbase + nt * 16 + l15;
            short8 wr = ld8(Whh0b + c * 256 + k0);
            short8 wz = ld8(Whh0b + (256 + c) * 256 + k0);
            short8 wn = ld8(Whh0b + (512 + c) * 256 + k0);
#pragma unroll
            for (int mt = 0; mt < 2; ++mt) {
                accr[mt][nt] = mfma16(af[mt], wr, accr[mt][nt]);
                accz[mt][nt] = mfma16(af[mt], wz, accz[mt][nt]);
                acch[mt][nt] = mfma16(af[mt], wn, acch[mt][nt]);
            }
        }
    }
    if (step > 0) {
        // action GEMM, K=8 padded into one K=32 chunk (quads 1-3 contribute 0)
        const short8 sz8 = {0,0,0,0,0,0,0,0};
        short8 af[2];
#pragma unroll
        for (int mt = 0; mt < 2; ++mt) {
            short8 v = ld8(abuf + (row0 + mt * 16 + l15) * 8);
            af[mt] = (q == 0) ? v : sz8;
        }
#pragma unroll
        for (int nt = 0; nt < 2; ++nt) {
            const int c = cbase + nt * 16 + l15;
            short8 wr = ld8(Wih0b + c * 8);
            short8 wz = ld8(Wih0b + (256 + c) * 8);
            short8 wn = ld8(Wih0b + (512 + c) * 8);
#pragma unroll
            for (int mt = 0; mt < 2; ++mt) {
                accr[mt][nt] = mfma16(af[mt], wr, accr[mt][nt]);
                accz[mt][nt] = mfma16(af[mt], wz, accz[mt][nt]);
                acci[mt][nt] = mfma16(af[mt], wn, acci[mt][nt]);
            }
        }
    }
#pragma unroll
    for (int nt = 0; nt < 2; ++nt) {
        const int c = cbase + nt * 16 + l15;
        const float br = bih0[c] + bhh0[c];
        const float bz = bih0[256 + c] + bhh0[256 + c];
        const float bi = bih0[512 + c];
        const float bh = bhh0[512 + c];
#pragma unroll
        for (int mt = 0; mt < 2; ++mt)
#pragma unroll
            for (int r = 0; r < 4; ++r) {
                const int grow = row0 + mt * 16 + q * 4 + r;
                const float rr = sigm(accr[mt][nt][r] + br);
                const float zz = sigm(accz[mt][nt][r] + bz);
                const float nn = tanh_f(acci[mt][nt][r] + bi + rr * (acch[mt][nt][r] + bh));
                const float hold = bf2f(h0in[grow * 256 + c]);
                h0out[grow * 256 + c] = f2bf((1.f - zz) * nn + zz * hold);
            }
    }
}

// ---------------- GRU cell 1: x = h0n, h = h1 ----------------------------------
__global__ __launch_bounds__(512) void k_gru1(
    const unsigned short* __restrict__ h0n, const unsigned short* __restrict__ h1in,
    unsigned short* __restrict__ h1out,
    const unsigned short* __restrict__ Wih1b, const unsigned short* __restrict__ Whh1b,
    const float* __restrict__ bih1, const float* __restrict__ bhh1)
{
    const int tid = threadIdx.x, lane = tid & 63, w = tid >> 6;
    const int rowg = w >> 1, colg = w & 1;
    const int row0 = blockIdx.x * 128 + rowg * 32;
    const int cbase = blockIdx.y * 64 + colg * 32;
    const int l15 = lane & 15, q = lane >> 4;
    const fvec4 fz = {0.f, 0.f, 0.f, 0.f};
    fvec4 accr[2][2], accz[2][2], acci[2][2], acch[2][2];
#pragma unroll
    for (int a = 0; a < 2; ++a)
#pragma unroll
        for (int b = 0; b < 2; ++b) { accr[a][b]=fz; accz[a][b]=fz; acci[a][b]=fz; acch[a][b]=fz; }

    for (int kc = 0; kc < 8; ++kc) {
        const int k0 = kc * 32 + q * 8;
        short8 ai[2], ah[2];
#pragma unroll
        for (int mt = 0; mt < 2; ++mt) {
            const int grow = row0 + mt * 16 + l15;
            ai[mt] = ld8(h0n  + grow * 256 + k0);
            ah[mt] = ld8(h1in + grow * 256 + k0);
        }
#pragma unroll
        for (int nt = 0; nt < 2; ++nt) {
            const int c = cbase + nt * 16 + l15;
            short8 wir = ld8(Wih1b + c * 256 + k0);
            short8 whr = ld8(Whh1b + c * 256 + k0);
            short8 wiz = ld8(Wih1b + (256 + c) * 256 + k0);
            short8 whz = ld8(Whh1b + (256 + c) * 256 + k0);
            short8 win = ld8(Wih1b + (512 + c) * 256 + k0);
            short8 whn = ld8(Whh1b + (512 + c) * 256 + k0);
#pragma unroll
            for (int mt = 0; mt < 2; ++mt) {
                accr[mt][nt] = mfma16(ai[mt], wir, accr[mt][nt]);
                accr[mt][nt] = mfma16(ah[mt], whr, accr[mt][nt]);
                accz[mt][nt] = mfma16(ai[mt], wiz, accz[mt][nt]);
                accz[mt][nt] = mfma16(ah[mt], whz, accz[mt][nt]);
                acci[mt][nt] = mfma16(ai[mt], win, acci[mt][nt]);
                acch[mt][nt] = mfma16(ah[mt], whn, acch[mt][nt]);
            }
        }
    }
#pragma unroll
    for (int nt = 0; nt < 2; ++nt) {
        const int c = cbase + nt * 16 + l15;
        const float br = bih1[c] + bhh1[c];
        const float bz = bih1[256 + c] + bhh1[256 + c];
        const float bi = bih1[512 + c];
        const float bh = bhh1[512 + c];
#pragma unroll
        for (int mt = 0; mt < 2; ++mt)
#pragma unroll
            for (int r = 0; r < 4; ++r) {
                const int grow = row0 + mt * 16 + q * 4 + r;
                const float rr = sigm(accr[mt][nt][r] + br);
                const float zz = sigm(accz[mt][nt][r] + bz);
                const float nn = tanh_f(acci[mt][nt][r] + bi + rr * (acch[mt][nt][r] + bh));
                const float hold = bf2f(h1in[grow * 256 + c]);
                h1out[grow * 256 + c] = f2bf((1.f - zz) * nn + zz * hold);
            }
    }
}

// ---------------- logits = h1n @ Wa^T + ba; out + softmax -> a_next ------------
// 256 thr = 32 rows/block; thread -> (row, j); j in lane bits 0-2.
__global__ __launch_bounds__(256) void k_logits(
    const unsigned short* __restrict__ h1n, const unsigned short* __restrict__ Wab,
    const float* __restrict__ ba, float* __restrict__ out, const int t,
    unsigned short* __restrict__ abuf)
{
    const int tid = threadIdx.x;
    const int row = blockIdx.x * 32 + (tid >> 3);
    const int j = tid & 7;
    float s = ba[j];
    for (int k8 = 0; k8 < 32; ++k8) {
        short8 h = ld8(h1n + row * 256 + k8 * 8);
        short8 wv = ld8(Wab + j * 256 + k8 * 8);
#pragma unroll
        for (int i = 0; i < 8; ++i)
            s += bf2f((unsigned short)h[i]) * bf2f((unsigned short)wv[i]);
    }
    float m = s;
    m = fmaxf(m, __shfl_xor(m, 1, 64));
    m = fmaxf(m, __shfl_xor(m, 2, 64));
    m = fmaxf(m, __shfl_xor(m, 4, 64));
    float e = __expf(s - m);
    float ssum = e;
    ssum += __shfl_xor(ssum, 1, 64);
    ssum += __shfl_xor(ssum, 2, 64);
    ssum += __shfl_xor(ssum, 4, 64);
    out[row * 80 + t * 8 + j] = s;                       // pre-softmax logits
    abuf[row * 8 + j] = f2bf(e * __builtin_amdgcn_rcpf(ssum));
}

// ---------------- host side ----------------------------------------------------
extern "C" void kernel_launch(void* const* d_in, const int* in_sizes, int n_in,
                              void* d_out, int out_size, void* d_ws, size_t ws_size,
                              hipStream_t stream)
{
    const float* ini   = (const float*)d_in[0];
    const float* fin   = (const float*)d_in[1];
    /* d_in[2] = horizon (always 10) */
    const float* W1    = (const float*)d_in[3];
    const float* b1    = (const float*)d_in[4];
    const float* lng   = (const float*)d_in[5];
    const float* lnb   = (const float*)d_in[6];
    const float* W2    = (const float*)d_in[7];
    const float* b2    = (const float*)d_in[8];
    const float* Wih0  = (const float*)d_in[9];
    const float* Whh0  = (const float*)d_in[10];
    const float* bih0  = (const float*)d_in[11];
    const float* bhh0  = (const float*)d_in[12];
    const float* Wih1  = (const float*)d_in[13];
    const float* Whh1  = (const float*)d_in[14];
    const float* bih1  = (const float*)d_in[15];
    const float* bhh1  = (const float*)d_in[16];
    const float* Wa    = (const float*)d_in[17];
    const float* ba    = (const float*)d_in[18];
    const float* Winit = (const float*)d_in[19];
    const float* binit = (const float*)d_in[20];
    float* out = (float*)d_out;

    char* ws = (char*)d_ws;
    unsigned short* wb     = (unsigned short*)ws;
    unsigned short* W1b    = wb;
    unsigned short* W2b    = wb + 262144;
    unsigned short* Winitb = wb + 327680;
    unsigned short* Wih0b  = wb + 458752;
    unsigned short* Whh0b  = wb + 464896;
    unsigned short* Wih1b  = wb + 661504;
    unsigned short* Whh1b  = wb + 858112;
    unsigned short* Wab    = wb + 1054720;
    unsigned short* hbuf = (unsigned short*)(ws + 2113536);
    unsigned short* h0a  = (unsigned short*)(ws + 18890752);
    unsigned short* h0b  = (unsigned short*)(ws + 35667968);
    unsigned short* h1a  = (unsigned short*)(ws + 52445184);
    unsigned short* h1b  = (unsigned short*)(ws + 69222400);
    unsigned short* abuf = (unsigned short*)(ws + 85999616);

    k_prep<<<dim3(4128), dim3(256), 0, stream>>>(W1, W2, Winit, Wih0, Whh0, Wih1, Whh1, Wa, wb);
    k_fc1<<<dim3(512), dim3(512), 0, stream>>>(ini, fin, W1b, b1, lng, lnb, hbuf);
    k_fc2<<<dim3(512), dim3(512), 0, stream>>>(hbuf, W2b, b2, hbuf);
    k_init<<<dim3(256, 4), dim3(512), 0, stream>>>(hbuf, Winitb, binit, h0a, h1a);

    unsigned short* h0c = h0a; unsigned short* h0n = h0b;
    unsigned short* h1c = h1a; unsigned short* h1n = h1b;
    for (int t = 0; t < 10; ++t) {
        k_gru0<<<dim3(256, 4), dim3(512), 0, stream>>>(h0c, h0n, abuf, t, Whh0b, Wih0b, bih0, bhh0);
        k_gru1<<<dim3(256, 4), dim3(512), 0, stream>>>(h0n, h1c, h1n, Wih1b, Whh1b, bih1, bhh1);
        k_logits<<<dim3(1024), dim3(256), 0, stream>>>(h1n, Wab, ba, out, t, abuf);
        unsigned short* tmp;
        tmp = h0c; h0c = h0n; h0n = tmp;
        tmp = h1c; h1c = h1n; h1n = tmp;
    }
}

// Round 2
// 1981.056 us; speedup vs baseline: 1.2376x; 1.2376x over previous
//
#include <hip/hip_runtime.h>

// InverseTransitionModel, B=32768, H=256, 10 GRU steps.
// v2: whole rollout fused into ONE kernel (block owns 64 rows; h0/h1/a live in
// LDS across all 10 steps; in-place updates guarded by barrier pairs).
// Encoder (fc1+LN+ReLU+fc2+ReLU+init) fused into one kernel via LDS.
// bf16 MFMA 16x16x32 everywhere, fp32 accum/elementwise.

#define HS 264   // LDS row stride in shorts (264*2=528 B, 16B aligned, odd-ish banks)

typedef __attribute__((ext_vector_type(8))) short short8;
typedef __attribute__((ext_vector_type(4))) float fvec4;

__device__ __forceinline__ float bf2f(unsigned short u) {
    union { unsigned int u; float f; } x; x.u = ((unsigned int)u) << 16; return x.f;
}
__device__ __forceinline__ unsigned short f2bf(float f) {
    union { float f; unsigned int u; } x; x.f = f;
    unsigned int r = x.u + 0x7fffu + ((x.u >> 16) & 1u);   // RNE
    return (unsigned short)(r >> 16);
}
__device__ __forceinline__ float sigm(float x)   { return __builtin_amdgcn_rcpf(1.f + __expf(-x)); }
__device__ __forceinline__ float tanh_f(float x) { return 2.f * __builtin_amdgcn_rcpf(1.f + __expf(-2.f * x)) - 1.f; }

__device__ __forceinline__ short8 ld8(const unsigned short* p) {
    return *reinterpret_cast<const short8*>(p);
}
__device__ __forceinline__ fvec4 mfma16(short8 a, short8 b, fvec4 c) {
    return __builtin_amdgcn_mfma_f32_16x16x32_bf16(a, b, c, 0, 0, 0);
}

// ---------------- weight cast fp32 -> bf16 (unchanged, works) ----------------
// ws short layout: W1[262144] W2[65536] Winit[131072] Wih0[6144]
//                  Whh0[196608] Wih1[196608] Whh1[196608] Wa[2048]
__global__ __launch_bounds__(256) void k_prep(
    const float* __restrict__ W1, const float* __restrict__ W2,
    const float* __restrict__ Winit, const float* __restrict__ Wih0,
    const float* __restrict__ Whh0, const float* __restrict__ Wih1,
    const float* __restrict__ Whh1, const float* __restrict__ Wa,
    unsigned short* __restrict__ wb)
{
    int i = blockIdx.x * 256 + threadIdx.x;
    if (i >= 1056768) return;
    float v;
    if      (i <  262144) v = W1[i];
    else if (i <  327680) v = W2[i - 262144];
    else if (i <  458752) v = Winit[i - 327680];
    else if (i <  464896) v = Wih0[i - 458752];
    else if (i <  661504) v = Whh0[i - 464896];
    else if (i <  858112) v = Wih1[i - 661504];
    else if (i < 1054720) v = Whh1[i - 858112];
    else                  v = Wa[i - 1054720];
    wb[i] = f2bf(v);
}

// ---------------- encoder: fc1 -> LN -> ReLU -> fc2 -> ReLU -> init -----------
// block = 64 rows, 8 waves; wave w owns cols [w*32, w*32+32) (fc1/fc2) and
// [w*64, w*64+64) (init). Intermediates round-trip through LDS (hb).
__global__ __launch_bounds__(512, 2) void k_encode(
    const float* __restrict__ ini, const float* __restrict__ fin,
    const unsigned short* __restrict__ W1b, const float* __restrict__ b1,
    const float* __restrict__ lng, const float* __restrict__ lnb,
    const unsigned short* __restrict__ W2b, const float* __restrict__ b2,
    const unsigned short* __restrict__ Winitb, const float* __restrict__ binit,
    unsigned short* __restrict__ h0g, unsigned short* __restrict__ h1g)
{
    __shared__ unsigned short hb[64 * HS];
    __shared__ float ps[64][8][2];
    __shared__ float st[64][2];
    const int tid = threadIdx.x, lane = tid & 63, w = tid >> 6;
    const int l15 = lane & 15, q = lane >> 4;
    const int rows0 = blockIdx.x * 64;
    const int c0 = w * 32;
    const fvec4 fz = {0.f, 0.f, 0.f, 0.f};

    // ---- fc1: [64,1024] @ W1^T ----
    fvec4 acc[4][2];
#pragma unroll
    for (int rt = 0; rt < 4; ++rt) { acc[rt][0] = fz; acc[rt][1] = fz; }
    for (int kc = 0; kc < 32; ++kc) {
        const int k0 = kc * 32 + q * 8;
        short8 a8[4];
#pragma unroll
        for (int rt = 0; rt < 4; ++rt) {
            const int grow = rows0 + rt * 16 + l15;
            const float* src = (k0 < 512) ? (ini + grow * 512 + k0)
                                          : (fin + grow * 512 + (k0 - 512));
            fvec4 v0 = *reinterpret_cast<const fvec4*>(src);
            fvec4 v1 = *reinterpret_cast<const fvec4*>(src + 4);
            short8 t;
            t[0]=(short)f2bf(v0[0]); t[1]=(short)f2bf(v0[1]); t[2]=(short)f2bf(v0[2]); t[3]=(short)f2bf(v0[3]);
            t[4]=(short)f2bf(v1[0]); t[5]=(short)f2bf(v1[1]); t[6]=(short)f2bf(v1[2]); t[7]=(short)f2bf(v1[3]);
            a8[rt] = t;
        }
#pragma unroll
        for (int ct = 0; ct < 2; ++ct) {
            short8 b8 = ld8(W1b + (c0 + ct * 16 + l15) * 1024 + k0);
#pragma unroll
            for (int rt = 0; rt < 4; ++rt) acc[rt][ct] = mfma16(a8[rt], b8, acc[rt][ct]);
        }
    }
    // ---- bias + LN stats ----
    float bv[2] = { b1[c0 + l15], b1[c0 + 16 + l15] };
#pragma unroll
    for (int rt = 0; rt < 4; ++rt)
#pragma unroll
        for (int r = 0; r < 4; ++r) {
            float s = 0.f, s2 = 0.f;
#pragma unroll
            for (int ct = 0; ct < 2; ++ct) {
                float v = acc[rt][ct][r] + bv[ct];
                acc[rt][ct][r] = v;
                s += v; s2 += v * v;
            }
#pragma unroll
            for (int off = 1; off < 16; off <<= 1) {
                s  += __shfl_xor(s,  off, 64);
                s2 += __shfl_xor(s2, off, 64);
            }
            if (l15 == 0) {
                int row = rt * 16 + q * 4 + r;
                ps[row][w][0] = s; ps[row][w][1] = s2;
            }
        }
    __syncthreads();
    if (tid < 64) {
        float s = 0.f, s2 = 0.f;
#pragma unroll
        for (int j = 0; j < 8; ++j) { s += ps[tid][j][0]; s2 += ps[tid][j][1]; }
        float mu = s * (1.f / 256.f);
        float var = s2 * (1.f / 256.f) - mu * mu;
        st[tid][0] = mu; st[tid][1] = rsqrtf(var + 1e-5f);
    }
    __syncthreads();
    {
        float gv[2]  = { lng[c0 + l15], lng[c0 + 16 + l15] };
        float bbv[2] = { lnb[c0 + l15], lnb[c0 + 16 + l15] };
#pragma unroll
        for (int rt = 0; rt < 4; ++rt)
#pragma unroll
            for (int ct = 0; ct < 2; ++ct)
#pragma unroll
                for (int r = 0; r < 4; ++r) {
                    int row = rt * 16 + q * 4 + r;
                    float v = (acc[rt][ct][r] - st[row][0]) * st[row][1] * gv[ct] + bbv[ct];
                    v = fmaxf(v, 0.f);
                    hb[row * HS + c0 + ct * 16 + l15] = f2bf(v);
                }
    }
    __syncthreads();
    // ---- fc2: relu(hb @ W2^T + b2), in-place on hb ----
    fvec4 acc2[4][2];
#pragma unroll
    for (int rt = 0; rt < 4; ++rt) { acc2[rt][0] = fz; acc2[rt][1] = fz; }
    for (int kc = 0; kc < 8; ++kc) {
        const int k0 = kc * 32 + q * 8;
        short8 a8[4];
#pragma unroll
        for (int rt = 0; rt < 4; ++rt) a8[rt] = ld8(hb + (rt * 16 + l15) * HS + k0);
#pragma unroll
        for (int ct = 0; ct < 2; ++ct) {
            short8 b8 = ld8(W2b + (c0 + ct * 16 + l15) * 256 + k0);
#pragma unroll
            for (int rt = 0; rt < 4; ++rt) acc2[rt][ct] = mfma16(a8[rt], b8, acc2[rt][ct]);
        }
    }
    {
        float b2v[2] = { b2[c0 + l15], b2[c0 + 16 + l15] };
        unsigned short stg[4][2][4];
#pragma unroll
        for (int rt = 0; rt < 4; ++rt)
#pragma unroll
            for (int ct = 0; ct < 2; ++ct)
#pragma unroll
                for (int r = 0; r < 4; ++r)
                    stg[rt][ct][r] = f2bf(fmaxf(acc2[rt][ct][r] + b2v[ct], 0.f));
        __syncthreads();   // all fc2 reads of hb done
#pragma unroll
        for (int rt = 0; rt < 4; ++rt)
#pragma unroll
            for (int ct = 0; ct < 2; ++ct)
#pragma unroll
                for (int r = 0; r < 4; ++r)
                    hb[(rt * 16 + q * 4 + r) * HS + c0 + ct * 16 + l15] = stg[rt][ct][r];
    }
    __syncthreads();
    // ---- init: hb @ Winit^T + binit -> h0g/h1g (torch view interleave) ----
    const int c0i = w * 64;
    fvec4 a3[4][4];
#pragma unroll
    for (int rt = 0; rt < 4; ++rt)
#pragma unroll
        for (int ct = 0; ct < 4; ++ct) a3[rt][ct] = fz;
    for (int kc = 0; kc < 8; ++kc) {
        const int k0 = kc * 32 + q * 8;
        short8 a8[4];
#pragma unroll
        for (int rt = 0; rt < 4; ++rt) a8[rt] = ld8(hb + (rt * 16 + l15) * HS + k0);
#pragma unroll
        for (int ct = 0; ct < 4; ++ct) {
            short8 b8 = ld8(Winitb + (c0i + ct * 16 + l15) * 256 + k0);
#pragma unroll
            for (int rt = 0; rt < 4; ++rt) a3[rt][ct] = mfma16(a8[rt], b8, a3[rt][ct]);
        }
    }
#pragma unroll
    for (int ct = 0; ct < 4; ++ct) {
        const int j = c0i + ct * 16 + l15;
        const float bz = binit[j];
        const int half = j >> 8, cc = j & 255;
#pragma unroll
        for (int rt = 0; rt < 4; ++rt)
#pragma unroll
            for (int r = 0; r < 4; ++r) {
                const int i = rows0 + rt * 16 + q * 4 + r;
                const unsigned short v = f2bf(a3[rt][ct][r] + bz);
                if (i < 16384) h0g[(2 * i + half) * 256 + cc] = v;
                else           h1g[(2 * (i - 16384) + half) * 256 + cc] = v;
            }
    }
}

// ---------------- fused 10-step rollout -----------------------------------
// block = 64 rows, 8 waves; wave w owns hidden cols [w*32, w*32+32).
// h0/h1/a live in LDS for all steps; in-place updates with barrier pairs.
__global__ __launch_bounds__(512, 2) void k_roll(
    const unsigned short* __restrict__ h0g, const unsigned short* __restrict__ h1g,
    const unsigned short* __restrict__ Wih0b, const unsigned short* __restrict__ Whh0b,
    const unsigned short* __restrict__ Wih1b, const unsigned short* __restrict__ Whh1b,
    const unsigned short* __restrict__ Wab,
    const float* __restrict__ bih0, const float* __restrict__ bhh0,
    const float* __restrict__ bih1, const float* __restrict__ bhh1,
    const float* __restrict__ ba, float* __restrict__ out)
{
    __shared__ unsigned short h0s[64 * HS];
    __shared__ unsigned short h1s[64 * HS];
    __shared__ unsigned short avs[64 * 8];
    const int tid = threadIdx.x, lane = tid & 63, w = tid >> 6;
    const int l15 = lane & 15, q = lane >> 4;
    const int rows0 = blockIdx.x * 64;
    const int c0 = w * 32;
    const fvec4 fz = {0.f, 0.f, 0.f, 0.f};
    const short8 z8 = {0,0,0,0,0,0,0,0};

    // ---- load h state global -> LDS ----
    {
        const int row = tid >> 3, seg = tid & 7;
        const unsigned short* g0 = h0g + (rows0 + row) * 256 + seg * 32;
        const unsigned short* g1 = h1g + (rows0 + row) * 256 + seg * 32;
        unsigned short* d0 = h0s + row * HS + seg * 32;
        unsigned short* d1 = h1s + row * HS + seg * 32;
#pragma unroll
        for (int j = 0; j < 4; ++j) {
            *reinterpret_cast<short8*>(d0 + j * 8) = ld8(g0 + j * 8);
            *reinterpret_cast<short8*>(d1 + j * 8) = ld8(g1 + j * 8);
        }
    }
    // ---- per-lane constants (steps share them) ----
    float br0[2], bz0[2], bi0[2], bh0[2], br1[2], bz1[2], bi1[2], bh1[2];
#pragma unroll
    for (int ct = 0; ct < 2; ++ct) {
        const int c = c0 + ct * 16 + l15;
        br0[ct] = bih0[c] + bhh0[c];
        bz0[ct] = bih0[256 + c] + bhh0[256 + c];
        bi0[ct] = bih0[512 + c];
        bh0[ct] = bhh0[512 + c];
        br1[ct] = bih1[c] + bhh1[c];
        bz1[ct] = bih1[256 + c] + bhh1[256 + c];
        bi1[ct] = bih1[512 + c];
        bh1[ct] = bhh1[512 + c];
    }
    const float bav = ba[l15 & 7];
    __syncthreads();

    for (int t = 0; t < 10; ++t) {
        // ================= GRU cell 0 =================
        fvec4 aR[4][2], aZ[4][2], aNi[4][2], aNh[4][2];
#pragma unroll
        for (int rt = 0; rt < 4; ++rt)
#pragma unroll
            for (int ct = 0; ct < 2; ++ct) { aR[rt][ct]=fz; aZ[rt][ct]=fz; aNi[rt][ct]=fz; aNh[rt][ct]=fz; }
        for (int kc = 0; kc < 8; ++kc) {
            const int k0 = kc * 32 + q * 8;
            short8 ah[4];
#pragma unroll
            for (int rt = 0; rt < 4; ++rt) ah[rt] = ld8(h0s + (rt * 16 + l15) * HS + k0);
#pragma unroll
            for (int ct = 0; ct < 2; ++ct) {
                const unsigned short* wp = Whh0b + (c0 + ct * 16 + l15) * 256 + k0;
                short8 wr = ld8(wp);
                short8 wz = ld8(wp + 65536);
                short8 wn = ld8(wp + 131072);
#pragma unroll
                for (int rt = 0; rt < 4; ++rt) {
                    aR[rt][ct]  = mfma16(ah[rt], wr, aR[rt][ct]);
                    aZ[rt][ct]  = mfma16(ah[rt], wz, aZ[rt][ct]);
                    aNh[rt][ct] = mfma16(ah[rt], wn, aNh[rt][ct]);
                }
            }
        }
        if (t > 0) {       // action GEMM K=8 in one K=32 chunk (quads 1-3 -> 0)
            short8 av[4];
#pragma unroll
            for (int rt = 0; rt < 4; ++rt) {
                short8 v = ld8(avs + (rt * 16 + l15) * 8);
                av[rt] = (q == 0) ? v : z8;
            }
#pragma unroll
            for (int ct = 0; ct < 2; ++ct) {
                const unsigned short* wp = Wih0b + (c0 + ct * 16 + l15) * 8;
                short8 wr = ld8(wp);
                short8 wz = ld8(wp + 2048);
                short8 wn = ld8(wp + 4096);
#pragma unroll
                for (int rt = 0; rt < 4; ++rt) {
                    aR[rt][ct]  = mfma16(av[rt], wr, aR[rt][ct]);
                    aZ[rt][ct]  = mfma16(av[rt], wz, aZ[rt][ct]);
                    aNi[rt][ct] = mfma16(av[rt], wn, aNi[rt][ct]);
                }
            }
        }
        {
            unsigned short hn[4][2][4];
#pragma unroll
            for (int rt = 0; rt < 4; ++rt)
#pragma unroll
                for (int ct = 0; ct < 2; ++ct)
#pragma unroll
                    for (int r = 0; r < 4; ++r) {
                        const int row = rt * 16 + q * 4 + r;
                        const int col = c0 + ct * 16 + l15;
                        const float hold = bf2f(h0s[row * HS + col]);
                        const float rr = sigm(aR[rt][ct][r] + br0[ct]);
                        const float zz = sigm(aZ[rt][ct][r] + bz0[ct]);
                        const float nn = tanh_f(aNi[rt][ct][r] + bi0[ct] + rr * (aNh[rt][ct][r] + bh0[ct]));
                        hn[rt][ct][r] = f2bf((1.f - zz) * nn + zz * hold);
                    }
            __syncthreads();   // everyone done reading h0s
#pragma unroll
            for (int rt = 0; rt < 4; ++rt)
#pragma unroll
                for (int ct = 0; ct < 2; ++ct)
#pragma unroll
                    for (int r = 0; r < 4; ++r)
                        h0s[(rt * 16 + q * 4 + r) * HS + c0 + ct * 16 + l15] = hn[rt][ct][r];
            __syncthreads();   // h0s = h0n
        }
        // ================= GRU cell 1 =================
#pragma unroll
        for (int rt = 0; rt < 4; ++rt)
#pragma unroll
            for (int ct = 0; ct < 2; ++ct) { aR[rt][ct]=fz; aZ[rt][ct]=fz; aNi[rt][ct]=fz; aNh[rt][ct]=fz; }
        for (int kc = 0; kc < 8; ++kc) {
            const int k0 = kc * 32 + q * 8;
            short8 ai[4], ah[4];
#pragma unroll
            for (int rt = 0; rt < 4; ++rt) {
                ai[rt] = ld8(h0s + (rt * 16 + l15) * HS + k0);
                ah[rt] = ld8(h1s + (rt * 16 + l15) * HS + k0);
            }
#pragma unroll
            for (int ct = 0; ct < 2; ++ct) {
                const unsigned short* wi = Wih1b + (c0 + ct * 16 + l15) * 256 + k0;
                const unsigned short* wh = Whh1b + (c0 + ct * 16 + l15) * 256 + k0;
                short8 wir = ld8(wi);
                short8 whr = ld8(wh);
                short8 wiz = ld8(wi + 65536);
                short8 whz = ld8(wh + 65536);
                short8 win = ld8(wi + 131072);
                short8 whn = ld8(wh + 131072);
#pragma unroll
                for (int rt = 0; rt < 4; ++rt) {
                    aR[rt][ct]  = mfma16(ai[rt], wir, aR[rt][ct]);
                    aR[rt][ct]  = mfma16(ah[rt], whr, aR[rt][ct]);
                    aZ[rt][ct]  = mfma16(ai[rt], wiz, aZ[rt][ct]);
                    aZ[rt][ct]  = mfma16(ah[rt], whz, aZ[rt][ct]);
                    aNi[rt][ct] = mfma16(ai[rt], win, aNi[rt][ct]);
                    aNh[rt][ct] = mfma16(ah[rt], whn, aNh[rt][ct]);
                }
            }
        }
        {
            unsigned short hn[4][2][4];
#pragma unroll
            for (int rt = 0; rt < 4; ++rt)
#pragma unroll
                for (int ct = 0; ct < 2; ++ct)
#pragma unroll
                    for (int r = 0; r < 4; ++r) {
                        const int row = rt * 16 + q * 4 + r;
                        const int col = c0 + ct * 16 + l15;
                        const float hold = bf2f(h1s[row * HS + col]);
                        const float rr = sigm(aR[rt][ct][r] + br1[ct]);
                        const float zz = sigm(aZ[rt][ct][r] + bz1[ct]);
                        const float nn = tanh_f(aNi[rt][ct][r] + bi1[ct] + rr * (aNh[rt][ct][r] + bh1[ct]));
                        hn[rt][ct][r] = f2bf((1.f - zz) * nn + zz * hold);
                    }
            __syncthreads();   // everyone done reading h1s
#pragma unroll
            for (int rt = 0; rt < 4; ++rt)
#pragma unroll
                for (int ct = 0; ct < 2; ++ct)
#pragma unroll
                    for (int r = 0; r < 4; ++r)
                        h1s[(rt * 16 + q * 4 + r) * HS + c0 + ct * 16 + l15] = hn[rt][ct][r];
            __syncthreads();   // h1s = h1n
        }
        // ================= logits + softmax -> a (waves 0-3, 16 rows each) ====
        if (w < 4) {
            fvec4 f = fz;
            for (int kc = 0; kc < 8; ++kc) {
                const int k0 = kc * 32 + q * 8;
                short8 a8 = ld8(h1s + (w * 16 + l15) * HS + k0);
                short8 b8 = ld8(Wab + (l15 & 7) * 256 + k0);   // cols 8-15 dup, ignored
                f = mfma16(a8, b8, f);
            }
#pragma unroll
            for (int r = 0; r < 4; ++r) {
                float s = f[r] + bav;
                float m = s;
                m = fmaxf(m, __shfl_xor(m, 1, 64));
                m = fmaxf(m, __shfl_xor(m, 2, 64));
                m = fmaxf(m, __shfl_xor(m, 4, 64));
                float e = __expf(s - m);
                float se = e;
                se += __shfl_xor(se, 1, 64);
                se += __shfl_xor(se, 2, 64);
                se += __shfl_xor(se, 4, 64);
                if (l15 < 8) {
                    const int lrow = w * 16 + q * 4 + r;
                    out[(rows0 + lrow) * 80 + t * 8 + l15] = s;
                    avs[lrow * 8 + l15] = f2bf(e * __builtin_amdgcn_rcpf(se));
                }
            }
        }
        __syncthreads();   // a ready for next step
    }
}

// ---------------- host side -----------------------------------------------
extern "C" void kernel_launch(void* const* d_in, const int* in_sizes, int n_in,
                              void* d_out, int out_size, void* d_ws, size_t ws_size,
                              hipStream_t stream)
{
    const float* ini   = (const float*)d_in[0];
    const float* fin   = (const float*)d_in[1];
    /* d_in[2] = horizon (always 10) */
    const float* W1    = (const float*)d_in[3];
    const float* b1    = (const float*)d_in[4];
    const float* lng   = (const float*)d_in[5];
    const float* lnb   = (const float*)d_in[6];
    const float* W2    = (const float*)d_in[7];
    const float* b2    = (const float*)d_in[8];
    const float* Wih0  = (const float*)d_in[9];
    const float* Whh0  = (const float*)d_in[10];
    const float* bih0  = (const float*)d_in[11];
    const float* bhh0  = (const float*)d_in[12];
    const float* Wih1  = (const float*)d_in[13];
    const float* Whh1  = (const float*)d_in[14];
    const float* bih1  = (const float*)d_in[15];
    const float* bhh1  = (const float*)d_in[16];
    const float* Wa    = (const float*)d_in[17];
    const float* ba    = (const float*)d_in[18];
    const float* Winit = (const float*)d_in[19];
    const float* binit = (const float*)d_in[20];
    float* out = (float*)d_out;

    char* ws = (char*)d_ws;
    unsigned short* wb     = (unsigned short*)ws;
    unsigned short* W1b    = wb;
    unsigned short* W2b    = wb + 262144;
    unsigned short* Winitb = wb + 327680;
    unsigned short* Wih0b  = wb + 458752;
    unsigned short* Whh0b  = wb + 464896;
    unsigned short* Wih1b  = wb + 661504;
    unsigned short* Whh1b  = wb + 858112;
    unsigned short* Wab    = wb + 1054720;
    unsigned short* h0g = (unsigned short*)(ws + 2113536);
    unsigned short* h1g = (unsigned short*)(ws + 18890752);

    k_prep<<<dim3(4128), dim3(256), 0, stream>>>(W1, W2, Winit, Wih0, Whh0, Wih1, Whh1, Wa, wb);
    k_encode<<<dim3(512), dim3(512), 0, stream>>>(ini, fin, W1b, b1, lng, lnb, W2b, b2,
                                                  Winitb, binit, h0g, h1g);
    k_roll<<<dim3(512), dim3(512), 0, stream>>>(h0g, h1g, Wih0b, Whh0b, Wih1b, Whh1b, Wab,
                                                bih0, bhh0, bih1, bhh1, ba, out);
}